// Round 9
// baseline (173.368 us; speedup 1.0000x reference)
//
#include <hip/hip_runtime.h>

#define N_NODES 4096
#define IN_FEAT 256
#define N_HEADS 8
#define N_HIDDEN 64
#define OUT_FEAT (N_HEADS * N_HIDDEN)  // 512
#define NEG_SLOPE 0.2f

typedef _Float16 half8 __attribute__((ext_vector_type(8)));
typedef _Float16 h2 __attribute__((ext_vector_type(2)));
typedef float floatx4 __attribute__((ext_vector_type(4)));
typedef float floatx16 __attribute__((ext_vector_type(16)));
typedef float f4 __attribute__((ext_vector_type(4)));

// ---------------- fat producer: MFMA GEMM + epilogue | adj->bits ----------
// (validated R8-R12 kernel, unchanged)
__global__ __launch_bounds__(256) void produce(
    const float* __restrict__ H, const float* __restrict__ adj,
    const float* __restrict__ Wt, const float* __restrict__ a,
    _Float16* __restrict__ GT16, float* __restrict__ elT,
    _Float16* __restrict__ eR1h, _Float16* __restrict__ eR2h,
    unsigned long long* __restrict__ bits) {
  __shared__ _Float16 SM[4 * 64 * 64];  // 32 KB: Ah|Al|Bh|Bl
  const int t = threadIdx.x;
  const int bx = blockIdx.x, by = blockIdx.y;

  if (by >= 8) {
    const int c = bx * 8 + (by - 8);
    const size_t W0 = (size_t)c * 512;
    const int wv = t >> 6, lane = t & 63;
    for (int k0 = 0; k0 < 128; k0 += 8) {
      float v[8];
#pragma unroll
      for (int k = 0; k < 8; ++k)
        v[k] = adj[(W0 + wv * 128 + k0 + k) * 64 + lane];
#pragma unroll
      for (int k = 0; k < 8; ++k) {
        unsigned long long m = __ballot(v[k] != 0.f);
        if (lane == 0) bits[W0 + wv * 128 + k0 + k] = m;
      }
    }
    return;
  }

  _Float16* Ah = SM;
  _Float16* Al = SM + 4096;
  _Float16* Bh = SM + 8192;
  _Float16* Bl = SM + 12288;
  const int w = t >> 6, l = t & 63;
  const int n16 = l & 15, q = l >> 4;
  const int bi = bx, bo = by;
  const int m0 = bi * 64 + w * 16;

  floatx4 acc[4];
#pragma unroll
  for (int ct = 0; ct < 4; ++ct) acc[ct] = (floatx4)0.f;

  for (int kc = 0; kc < 4; ++kc) {
    if (kc) __syncthreads();
#pragma unroll
    for (int p = 0; p < 4; ++p) {
      const int idx = p * 256 + t;
      const int r = idx >> 4;
      const int c4 = (idx & 15) << 2;
      const int dst = r * 64 + ((((idx & 15) >> 1)) ^ (r & 7)) * 8 + (idx & 1) * 4;
      float4 hv = *(const float4*)(H + (size_t)(bi * 64 + r) * IN_FEAT + kc * 64 + c4);
      float4 wv = *(const float4*)(Wt + (size_t)(bo * 64 + r) * IN_FEAT + kc * 64 + c4);
      union { _Float16 h[4]; int2 d; } hh_, hl_, wh_, wl_;
      hh_.h[0] = (_Float16)hv.x; hh_.h[1] = (_Float16)hv.y;
      hh_.h[2] = (_Float16)hv.z; hh_.h[3] = (_Float16)hv.w;
      hl_.h[0] = (_Float16)(hv.x - (float)hh_.h[0]);
      hl_.h[1] = (_Float16)(hv.y - (float)hh_.h[1]);
      hl_.h[2] = (_Float16)(hv.z - (float)hh_.h[2]);
      hl_.h[3] = (_Float16)(hv.w - (float)hh_.h[3]);
      wh_.h[0] = (_Float16)wv.x; wh_.h[1] = (_Float16)wv.y;
      wh_.h[2] = (_Float16)wv.z; wh_.h[3] = (_Float16)wv.w;
      wl_.h[0] = (_Float16)(wv.x - (float)wh_.h[0]);
      wl_.h[1] = (_Float16)(wv.y - (float)wh_.h[1]);
      wl_.h[2] = (_Float16)(wv.z - (float)wh_.h[2]);
      wl_.h[3] = (_Float16)(wv.w - (float)wh_.h[3]);
      *(int2*)&Ah[dst] = hh_.d;
      *(int2*)&Al[dst] = hl_.d;
      *(int2*)&Bh[dst] = wh_.d;
      *(int2*)&Bl[dst] = wl_.d;
    }
    __syncthreads();
#pragma unroll
    for (int ks = 0; ks < 2; ++ks) {
      const int ao = (w * 16 + n16) * 64 + (((ks << 2) + q) ^ (n16 & 7)) * 8;
      half8 Afh = *(const half8*)&Ah[ao];
      half8 Afl = *(const half8*)&Al[ao];
#pragma unroll
      for (int ct = 0; ct < 4; ++ct) {
        const int bofs = (ct * 16 + n16) * 64 + (((ks << 2) + q) ^ (n16 & 7)) * 8;
        half8 Bfh = *(const half8*)&Bh[bofs];
        half8 Bfl = *(const half8*)&Bl[bofs];
        acc[ct] = __builtin_amdgcn_mfma_f32_16x16x32_f16(Afh, Bfh, acc[ct], 0, 0, 0);
        acc[ct] = __builtin_amdgcn_mfma_f32_16x16x32_f16(Afl, Bfh, acc[ct], 0, 0, 0);
        acc[ct] = __builtin_amdgcn_mfma_f32_16x16x32_f16(Afh, Bfl, acc[ct], 0, 0, 0);
      }
    }
  }

  float aLv[4], aRv[4];
#pragma unroll
  for (int ct = 0; ct < 4; ++ct) {
    aLv[ct] = a[ct * 16 + n16];
    aRv[ct] = a[64 + ct * 16 + n16];
  }
#pragma unroll
  for (int reg = 0; reg < 4; ++reg) {
    float sl = 0.f, sr = 0.f;
#pragma unroll
    for (int ct = 0; ct < 4; ++ct) {
      sl = fmaf(acc[ct][reg], aLv[ct], sl);
      sr = fmaf(acc[ct][reg], aRv[ct], sr);
    }
#pragma unroll
    for (int off = 1; off < 16; off <<= 1) {
      sl += __shfl_xor(sl, off);
      sr += __shfl_xor(sr, off);
    }
    if (n16 == 0) {
      const int rowi = m0 + q * 4 + reg;
      elT[(size_t)bo * N_NODES + rowi] = sl;
      eR1h[(size_t)bo * N_NODES + rowi] = (_Float16)__expf(sr);
      eR2h[(size_t)bo * N_NODES + rowi] = (_Float16)__expf(0.2f * sr);
    }
  }

  __syncthreads();
  _Float16* LG = SM;  // 64 x 72 halfs
#pragma unroll
  for (int ct = 0; ct < 4; ++ct)
#pragma unroll
    for (int reg = 0; reg < 4; ++reg)
      LG[(w * 16 + q * 4 + reg) * 72 + ct * 16 + n16] = (_Float16)acc[ct][reg];
  __syncthreads();
  {
    const int f = t >> 2, jq = t & 3;
    union { _Float16 hh[16]; int4 v[2]; } u;
#pragma unroll
    for (int k = 0; k < 16; ++k) u.hh[k] = LG[(jq * 16 + k) * 72 + f];
    _Float16* dst = GT16 + (size_t)(bo * 64 + f) * N_NODES + bi * 64 + jq * 16;
    *(int4*)dst = u.v[0];
    *(int4*)(dst + 8) = u.v[1];
  }
}

// ---------------- dense attention v17: v8 skeleton, 32x32x16, j-sub waves --
// R8 model: v8's 50us ~= serial sum of VALU 21.5 + DS 17-20 + MFMA 8 us;
// barrier-lockstep prevents cross-wave pipe overlap, and v8's 16x16 path
// makes both rt-waves read the SAME B-fragments (2x DS duplication). v17
// changes ONLY the wave decomposition: wave (jsub, jh) covers all 32 i-rows
// (M=32 via 32x32x16 MFMA) x 64 feats (2 MFMA) x a 32-j sub-window of the
// jh step-tile. B-reads per wave-step: 4 ds_read_b128 (was 8) -> DS ~10us.
// P-gen per lane unchanged (16 halfs/step, no duplication). Staging,
// swizzle (cg = ss^(ff&7)), per-step barrier, eRs/eL staging: byte-for-byte
// v8 (the validated 0-conflict layout). Read slot sl = jsub*4+ks*2+hi,
// physical sl^(c31&7): within a 16-lane phase all 8 bank-groups hit 2x =
// free. A/B/C 32x32 layouts + P-gen mask path: v9/v10/v11-validated.
// Epilogue: v11-exact 4-partial rotated-scratch combine (validated).
__global__ __launch_bounds__(256) void attn_v17(
    const unsigned long long* __restrict__ bits, const _Float16* __restrict__ GT16,
    const float* __restrict__ elT, const _Float16* __restrict__ eR1h,
    const _Float16* __restrict__ eR2h, float* __restrict__ out) {
  __shared__ __align__(16) _Float16 Gt[2][2][4096];   // [par][jh][64f x 64j], 32 KB
  __shared__ __align__(16) _Float16 eRs1[2][2][64];   // 512 B
  __shared__ __align__(16) _Float16 eRs2[2][2][64];   // 512 B
  __shared__ float eL1s[32], eL2s[32];
  __shared__ float Zp[4][32];

  const int t = threadIdx.x;
  const int ib = blockIdx.x, h = blockIdx.y;
  const int i0 = ib * 32;
  const int w = t >> 6, l = t & 63;
  const int c31 = l & 31, hi = l >> 5;
  const int jh = w >> 1, jsub = w & 1;

  // ---- Gt staging descriptors: v8-exact (call c stages chunk w*256+c*64+l)
  const _Float16* gsrcs[4];
  int ldsbase[4];
#pragma unroll
  for (int c = 0; c < 4; ++c) {
    const int flat = w * 256 + c * 64 + l;
    const int fjh = flat >> 9;
    const int ff = (flat >> 3) & 63;
    const int ss = flat & 7;
    const int cg = ss ^ (ff & 7);
    gsrcs[c] = GT16 + (size_t)(h * 64 + ff) * N_NODES + fjh * 2048 + cg * 8;
    ldsbase[c] = (w * 256 + c * 64) * 8;
  }
  // eR staging role (t < 32): v8-exact
  const int era = (t >> 3) & 1, erjh = t >> 4, erseg = t & 7;
  const _Float16* esrc0 = (era ? eR2h : eR1h) + (size_t)h * N_NODES + erjh * 2048 + erseg * 8;
  // bits: ull per step for row i0+c31, j-half jh (lanes 32-63 duplicate 0-31;
  // broadcast-cached)
  const unsigned long long* bp = bits + (size_t)(i0 + c31) * 64 + jh * 32;

  if (t < 32) {
    float e = elT[(size_t)h * N_NODES + i0 + t];
    eL1s[t] = __expf(e);
    eL2s[t] = __expf(0.2f * e);
  }
  // ---- stage step 0 into par=0 (v8-exact) ----
#pragma unroll
  for (int c = 0; c < 4; ++c)
    __builtin_amdgcn_global_load_lds(
        (const __attribute__((address_space(1))) unsigned int*)gsrcs[c],
        (__attribute__((address_space(3))) unsigned int*)(&Gt[0][0][0] + ldsbase[c]),
        16, 0, 0);
  if (t < 32) {
    int4 ev = *(const int4*)esrc0;
    *(int4*)&(era ? eRs2 : eRs1)[0][erjh][erseg * 8] = ev;
  }
  unsigned long long bvc = bp[0];
  __syncthreads();

  const _Float16 e1f = (_Float16)eL1s[c31];
  const _Float16 e2f = (_Float16)eL2s[c31];
  const h2 eL1h2 = {e1f, e1f};
  const h2 eL2h2 = {e2f, e2f};
  half8 Bones;  // 32x32 B with col 0 = 1
#pragma unroll
  for (int k = 0; k < 8; ++k) Bones[k] = (c31 == 0) ? (_Float16)1.f : (_Float16)0.f;

  floatx16 acc0 = (floatx16)0.f, acc1 = (floatx16)0.f, accZ = (floatx16)0.f;

  int par = 0;
  for (int step = 0; step < 32; ++step) {
    // ---- async-stage step+1 into other parity (v8-exact) ----
    int4 ev;
    unsigned long long bvn = bvc;
    if (step + 1 < 32) {
      const int np = par ^ 1;
#pragma unroll
      for (int c = 0; c < 4; ++c)
        __builtin_amdgcn_global_load_lds(
            (const __attribute__((address_space(1))) unsigned int*)(gsrcs[c] + (step + 1) * 64),
            (__attribute__((address_space(3))) unsigned int*)(&Gt[np][0][0] + ldsbase[c]),
            16, 0, 0);
      if (t < 32) ev = *(const int4*)(esrc0 + (step + 1) * 64);
      bvn = bp[step + 1];
    }
    // ---- compute current step: 2 K-chunks of 16 j (32x32x16 path) ----
    const _Float16* gt = &Gt[par][jh][0];
#pragma unroll
    for (int ks = 0; ks < 2; ++ks) {
      const int sl = jsub * 4 + ks * 2 + hi;   // logical 16B slot & bits byte
      const unsigned byte = (unsigned)(bvc >> (sl * 8)) & 0xffu;
      uint4 r1 = *(const uint4*)&eRs1[par][jh][sl * 8];
      uint4 r2 = *(const uint4*)&eRs2[par][jh][sl * 8];
      const unsigned r1a[4] = {r1.x, r1.y, r1.z, r1.w};
      const unsigned r2a[4] = {r2.x, r2.y, r2.z, r2.w};
      unsigned pr[4];
#pragma unroll
      for (int kk = 0; kk < 4; ++kk) {
        h2 pa = eL1h2 * __builtin_bit_cast(h2, r1a[kk]);
        h2 pb = eL2h2 * __builtin_bit_cast(h2, r2a[kk]);
        h2 pv = __builtin_elementwise_max(pa, pb);
        unsigned y = (byte >> (2 * kk)) & 3u;
        unsigned b01 = (y | (y << 15)) & 0x00010001u;
        unsigned keep = b01 * 0xffffu;
        pr[kk] = (__builtin_bit_cast(unsigned, pv) & keep) | (0x3C003C00u & ~keep);
      }
      const uint4 prv = {pr[0], pr[1], pr[2], pr[3]};
      half8 Af = __builtin_bit_cast(half8, prv);
      const int sp = (sl ^ (c31 & 7)) * 8;     // physical slot (swizzle)
      half8 B0 = *(const half8*)&gt[(c31)*64 + sp];
      half8 B1 = *(const half8*)&gt[(32 + c31) * 64 + sp];
      acc0 = __builtin_amdgcn_mfma_f32_32x32x16_f16(Af, B0, acc0, 0, 0, 0);
      acc1 = __builtin_amdgcn_mfma_f32_32x32x16_f16(Af, B1, acc1, 0, 0, 0);
      accZ = __builtin_amdgcn_mfma_f32_32x32x16_f16(Af, Bones, accZ, 0, 0, 0);
    }
    // ---- store staged eR regs; barrier drains global_load_lds + LDS ----
    if (step + 1 < 32 && t < 32)
      *(int4*)&(era ? eRs2 : eRs1)[par ^ 1][erjh][erseg * 8] = ev;
    bvc = bvn;
    __syncthreads();
    par ^= 1;
  }

  // ---- epilogue: combine 4 j-sub partials (v11-exact, validated) ----
  // fp32 scratch reuses Gt (32 KB = 4 x [32 rows][64 cols]); columns rotated
  // by row*4 to break the stride-64 bank alias on the float4 re-reads.
  float* sc = (float*)&Gt[0][0][0];
#pragma unroll
  for (int ft = 0; ft < 2; ++ft) {
#pragma unroll
    for (int r = 0; r < 16; ++r) {
      const int row = (r & 3) + 8 * (r >> 2) + 4 * hi;
      const int col = (ft * 32 + c31 + row * 4) & 63;
      sc[w * 2048 + row * 64 + col] = ft ? acc1[r] : acc0[r];
    }
  }
  if (c31 == 0) {
#pragma unroll
    for (int r = 0; r < 16; ++r)
      Zp[w][(r & 3) + 8 * (r >> 2) + 4 * hi] = accZ[r];
  }
  __syncthreads();
  {
    const int row = t >> 3, cg = (t & 7) * 8;
    const int sA = (cg + row * 4) & 63;
    const int sB = (cg + 4 + row * 4) & 63;
    f4 s0 = (f4)0.f, s1 = (f4)0.f;
#pragma unroll
    for (int w4 = 0; w4 < 4; ++w4) {
      s0 += *(const f4*)&sc[w4 * 2048 + row * 64 + sA];
      s1 += *(const f4*)&sc[w4 * 2048 + row * 64 + sB];
    }
    const float Z = Zp[0][row] + Zp[1][row] + Zp[2][row] + Zp[3][row];
    const float invz = 1.f / Z;
    s0 *= invz;
    s1 *= invz;
    float* op = out + (size_t)(i0 + row) * OUT_FEAT + h * 64 + cg;
    *(f4*)op = s0;
    *(f4*)(op + 4) = s1;
  }
}

extern "C" void kernel_launch(void* const* d_in, const int* in_sizes, int n_in,
                              void* d_out, int out_size, void* d_ws, size_t ws_size,
                              hipStream_t stream) {
  const float* h   = (const float*)d_in[0];
  const float* adj = (const float*)d_in[1];
  const float* W   = (const float*)d_in[2];
  const float* a   = (const float*)d_in[3];
  float* out = (float*)d_out;

  char* ws = (char*)d_ws;
  _Float16* GT16 = (_Float16*)ws;                                         // 4 MB
  unsigned long long* bits = (unsigned long long*)(ws + 4u * 1024 * 1024);// 2 MB
  float* elT = (float*)(ws + 6u * 1024 * 1024);                           // 128 KB
  _Float16* eR1h = (_Float16*)(ws + 6u * 1024 * 1024 + 128 * 1024);       // 64 KB
  _Float16* eR2h = (_Float16*)(ws + 6u * 1024 * 1024 + 192 * 1024);       // 64 KB

  produce<<<dim3(64, 16), 256, 0, stream>>>(h, adj, W, a, GT16, elT, eR1h, eR2h, bits);
  attn_v17<<<dim3(128, 8), 256, 0, stream>>>(bits, GT16, elT, eR1h, eR2h, out);
}